// Round 7
// baseline (2613.006 us; speedup 1.0000x reference)
//
#include <hip/hip_runtime.h>

typedef unsigned int uint;
typedef uint ui4v __attribute__((ext_vector_type(4)));
typedef float fx4 __attribute__((ext_vector_type(4)));
typedef short s8v __attribute__((ext_vector_type(8)));

// ---------- bf16 helpers ----------
__device__ __forceinline__ uint bfpack(float a, float b) {
  uint ua = __float_as_uint(a), ub = __float_as_uint(b);
  ua += 0x7fffu + ((ua >> 16) & 1u);   // RNE to bf16
  ub += 0x7fffu + ((ub >> 16) & 1u);
  return (ua >> 16) | (ub & 0xffff0000u);
}
__device__ __forceinline__ float bflo(uint d) { return __uint_as_float(d << 16); }
__device__ __forceinline__ float bfhi(uint d) { return __uint_as_float(d & 0xffff0000u); }

// ---------- K1: transition matrix in MFMA A-operand layout ----------
// State "identity" = (qd, i): lane quad qd owns orig states 32qd+i, i=0..31, for its chain.
// C-frag[t][reg] of lane quad qd  <-> orig state 32qd + 4t + reg      (C row = 16t+4qd+reg)
// B-frag[kt][j]  of lane quad qd  <-> orig state 32qd + 8kt + j       (hw k = 32kt+8qd+j)
// A element for tile (t,kt), lane (qd,c), j: hw (m=16t+c, k=32kt+8qd+j) must hold
//   P(orig_k -> orig_m) with orig_k = 32qd+8kt+j, orig_m = 32*(c>>2) + 4t + (c&3).
__global__ void k_tranA(const float* __restrict__ w, uint* __restrict__ Atbl) {
  __shared__ float rowLSE[128];
  int tid = threadIdx.x;                       // 128 threads
  const float4* w4 = (const float4*)(w + tid * 128);
  float se = 0.f;
  #pragma unroll 8
  for (int i = 0; i < 32; ++i) {
    float4 v = w4[i];
    se += __expf(v.x) + __expf(v.y) + __expf(v.z) + __expf(v.w);
  }
  rowLSE[tid] = __logf(se);                    // logits in (-1,1): shift-free LSE is fine
  __syncthreads();
  int l = tid & 63, tg = tid >> 6;
  int qdx = l >> 4, c = l & 15;
  int om0 = 32 * (c >> 2) + (c & 3);
  uint4* A4 = (uint4*)Atbl;
  for (int t = tg * 4; t < tg * 4 + 4; ++t) {
    int om = om0 + 4 * t;
    for (int kt = 0; kt < 4; ++kt) {
      int kb = 32 * qdx + 8 * kt;
      uint4 st;
      st.x = bfpack(__expf(w[(kb+0)*128+om]-rowLSE[kb+0]), __expf(w[(kb+1)*128+om]-rowLSE[kb+1]));
      st.y = bfpack(__expf(w[(kb+2)*128+om]-rowLSE[kb+2]), __expf(w[(kb+3)*128+om]-rowLSE[kb+3]));
      st.z = bfpack(__expf(w[(kb+4)*128+om]-rowLSE[kb+4]), __expf(w[(kb+5)*128+om]-rowLSE[kb+5]));
      st.w = bfpack(__expf(w[(kb+6)*128+om]-rowLSE[kb+6]), __expf(w[(kb+7)*128+om]-rowLSE[kb+7]));
      A4[(t * 4 + kt) * 64 + l] = st;
    }
  }
}

// ---------- K2a: logits (bf16, pair-linear layout) + per-k sum of exp(logit) ----------
__global__ __launch_bounds__(256) void k_logits(const float* __restrict__ emb,
    const float* __restrict__ vocab, uint* __restrict__ qtbl,
    float* __restrict__ S_glob, int V) {
  __shared__ float S_part[128];
  int tid = threadIdx.x;
  int kt = tid & 15, vt = tid >> 4;
  int k0 = kt * 8;
  int vbase = blockIdx.x * 64 + vt * 4;
  if (tid < 128) S_part[tid] = 0.f;
  __syncthreads();

  float acc[4][8];
  #pragma unroll
  for (int i = 0; i < 4; ++i)
    #pragma unroll
    for (int r = 0; r < 8; ++r) acc[i][r] = 0.f;

  int vidx[4];
  #pragma unroll
  for (int i = 0; i < 4; ++i) { int vv = vbase + i; vidx[i] = (vv < V) ? vv : (V - 1); }

  const float4* emb4 = (const float4*)emb;
  const float4* voc4 = (const float4*)vocab;
  for (int jb = 0; jb < 32; ++jb) {
    float4 e4[8];
    #pragma unroll
    for (int r = 0; r < 8; ++r) e4[r] = emb4[(k0 + r) * 32 + jb];
    #pragma unroll
    for (int i = 0; i < 4; ++i) {
      float4 va = voc4[(size_t)vidx[i] * 32 + jb];
      #pragma unroll
      for (int r = 0; r < 8; ++r)
        acc[i][r] += va.x * e4[r].x + va.y * e4[r].y + va.z * e4[r].z + va.w * e4[r].w;
    }
  }

  float sume[8];
  #pragma unroll
  for (int r = 0; r < 8; ++r) sume[r] = 0.f;
  #pragma unroll
  for (int i = 0; i < 4; ++i) {
    int vv = vbase + i;
    if (vv < V) {
      #pragma unroll
      for (int r = 0; r < 8; ++r) sume[r] += __expf(acc[i][r]);   // |logit| <~ 40 : safe
      uint4 st;
      st.x = bfpack(acc[i][0], acc[i][1]);
      st.y = bfpack(acc[i][2], acc[i][3]);
      st.z = bfpack(acc[i][4], acc[i][5]);
      st.w = bfpack(acc[i][6], acc[i][7]);
      *((uint4*)(qtbl + (size_t)vv * 64) + kt) = st;
    }
  }
  #pragma unroll
  for (int r = 0; r < 8; ++r) atomicAdd(&S_part[k0 + r], sume[r]);
  __syncthreads();
  if (tid < 128) atomicAdd(&S_glob[tid], S_part[tid]);
}

// ---------- K2c: in-place q[v][k] = exp(emis - Emax_v) (bf16), Emax table ----------
__global__ __launch_bounds__(256) void k_qtab(uint* __restrict__ qtbl,
    const float* __restrict__ S_glob, float* __restrict__ Emax, int V) {
  int tid = threadIdx.x;
  int l = tid & 63;
  int v = blockIdx.x * 4 + (tid >> 6);
  if (v >= V) return;
  float2 S2 = ((const float2*)S_glob)[l];
  float z0 = __logf(S2.x), z1 = __logf(S2.y);
  size_t off = (size_t)v * 64 + l;
  uint d = qtbl[off];
  float e0 = bflo(d) - z0, e1 = bfhi(d) - z1;
  float m = fmaxf(e0, e1);
  #pragma unroll
  for (int s = 1; s < 64; s <<= 1) m = fmaxf(m, __shfl_xor(m, s, 64));
  float q0 = __expf(e0 - m), q1 = __expf(e1 - m);
  qtbl[off] = bfpack(q0, q1);
  if (l == 0) Emax[v] = m;
}

// ---------- K3: MFMA scan. One wave = 16 chains. No LDS/barriers in the loop. ----------
#define BCV(v) __builtin_bit_cast(s8v, v)
#define MF(a, b, c) __builtin_amdgcn_mfma_f32_16x16x32_bf16(BCV(a), BCV(b), (c), 0, 0, 0)

#define REPAF(M) M(0,0) M(0,1) M(0,2) M(0,3) M(1,0) M(1,1) M(1,2) M(1,3) \
                 M(2,0) M(2,1) M(2,2) M(2,3) M(3,0) M(3,1) M(3,2) M(3,3) \
                 M(4,0) M(4,1) M(4,2) M(4,3) M(5,0) M(5,1) M(5,2) M(5,3) \
                 M(6,0) M(6,1) M(6,2) M(6,3) M(7,0) M(7,1) M(7,2) M(7,3)

#define DECL_AF(t,kt) ui4v af##t##kt;
#define LOAD_AF(t,kt) af##t##kt = Ap[((t)*4+(kt))*64 + l];
// AGPR pin: A-operands live in the ACC register class -> no ArchVGPR pressure, no spill.
#define PIN_AF(t,kt) asm volatile("" : "+a"(af##t##kt));

#define MTILE(t) \
  fx4 acc##t = MF(af##t##0, bq0, zz); \
  acc##t = MF(af##t##1, bq1, acc##t); \
  acc##t = MF(af##t##2, bq2, acc##t); \
  acc##t = MF(af##t##3, bq3, acc##t);

#define QMA(t, qv) acc##t.x *= bflo(qv.x); acc##t.y *= bfhi(qv.x); acc##t.z *= bflo(qv.y); acc##t.w *= bfhi(qv.y);
#define QMB(t, qv) acc##t.x *= bflo(qv.z); acc##t.y *= bfhi(qv.z); acc##t.z *= bflo(qv.w); acc##t.w *= bfhi(qv.w);

// sA = j&3 (token slot to load for t+4), sB = (j+2)&3 (token for q prefetch t+2), qp = j&1
#define STEP(j, sA, sB, qp) { \
  tk##sA = xrow[(tbase + (j) + 4) & 4095]; \
  MTILE(0) MTILE(1) MTILE(2) MTILE(3) MTILE(4) MTILE(5) MTILE(6) MTILE(7) \
  ui4v qva = qs##qp##_0, qvb = qs##qp##_1, qvc = qs##qp##_2, qvd = qs##qp##_3; \
  QMA(0, qva) QMB(1, qva) QMA(2, qvb) QMB(3, qvb) \
  QMA(4, qvc) QMB(5, qvc) QMA(6, qvd) QMB(7, qvd) \
  if ((j) == 7) {                                 /* exact renorm every 8 steps */ \
    fx4 s4 = ((acc0 + acc1) + (acc2 + acc3)) + ((acc4 + acc5) + (acc6 + acc7)); \
    float tt = (s4.x + s4.y) + (s4.z + s4.w); \
    tt += __shfl_xor(tt, 16, 64); tt += __shfl_xor(tt, 32, 64); \
    LLacc += __logf(tt); \
    float it = 1.0f / tt; \
    acc0 *= it; acc1 *= it; acc2 *= it; acc3 *= it; \
    acc4 *= it; acc5 *= it; acc6 *= it; acc7 *= it; \
  } \
  bq0.x = bfpack(acc0.x, acc0.y); bq0.y = bfpack(acc0.z, acc0.w); \
  bq0.z = bfpack(acc1.x, acc1.y); bq0.w = bfpack(acc1.z, acc1.w); \
  bq1.x = bfpack(acc2.x, acc2.y); bq1.y = bfpack(acc2.z, acc2.w); \
  bq1.z = bfpack(acc3.x, acc3.y); bq1.w = bfpack(acc3.z, acc3.w); \
  bq2.x = bfpack(acc4.x, acc4.y); bq2.y = bfpack(acc4.z, acc4.w); \
  bq2.z = bfpack(acc5.x, acc5.y); bq2.w = bfpack(acc5.z, acc5.w); \
  bq3.x = bfpack(acc6.x, acc6.y); bq3.y = bfpack(acc6.z, acc6.w); \
  bq3.z = bfpack(acc7.x, acc7.y); bq3.w = bfpack(acc7.z, acc7.w); \
  { const ui4v* qrp = (const ui4v*)(qtbl + (size_t)tk##sB * 64) + qd4; \
    qs##qp##_0 = qrp[0]; qs##qp##_1 = qrp[1]; qs##qp##_2 = qrp[2]; qs##qp##_3 = qrp[3]; } \
}

__global__ __attribute__((amdgpu_flat_work_group_size(64, 64), amdgpu_waves_per_eu(1, 1)))
void k_chain(const int* __restrict__ x,
    const float* __restrict__ start_w, const float* __restrict__ start_b,
    const uint* __restrict__ Atbl, const uint* __restrict__ qtbl,
    float* __restrict__ chainLL, int NN) {
  __shared__ uint u0tmp[64];
  int l = threadIdx.x;
  int qdx = l >> 4, c = l & 15, qd4 = qdx * 4;
  int chain = blockIdx.x * 16 + c;
  int cc = chain < NN ? chain : NN - 1;
  const int* xrow = x + (size_t)cc * 4096;
  const ui4v* Ap = (const ui4v*)Atbl;

  REPAF(DECL_AF)
  REPAF(LOAD_AF)
  REPAF(PIN_AF)

  // u0 = softmax(start_w + start_b) (same for every chain), LL0 = LSE(alpha0)
  float a0i = start_w[2 * l] + start_b[2 * l];
  float a1i = start_w[2 * l + 1] + start_b[2 * l + 1];
  float m = fmaxf(a0i, a1i);
  #pragma unroll
  for (int s = 1; s < 64; s <<= 1) m = fmaxf(m, __shfl_xor(m, s, 64));
  float p0 = __expf(a0i - m), p1 = __expf(a1i - m);
  float tot = p0 + p1;
  #pragma unroll
  for (int s = 1; s < 64; s <<= 1) tot += __shfl_xor(tot, s, 64);
  float LLacc = m + __logf(tot);
  float inv = 1.0f / tot;
  u0tmp[l] = bfpack(p0 * inv, p1 * inv);   // pair layout: dword l = states 2l,2l+1
  __syncthreads();
  // B-frag[kt] dword d = states 32qdx+8kt+2d,+1 = pair dword 16qdx+4kt+d
  ui4v bq0 = ((const ui4v*)u0tmp)[qd4 + 0];
  ui4v bq1 = ((const ui4v*)u0tmp)[qd4 + 1];
  ui4v bq2 = ((const ui4v*)u0tmp)[qd4 + 2];
  ui4v bq3 = ((const ui4v*)u0tmp)[qd4 + 3];

  fx4 zz; zz.x = 0.f; zz.y = 0.f; zz.z = 0.f; zz.w = 0.f;

  int tk0 = 0, tk1 = 0, tk2 = xrow[2], tk3 = xrow[3];
  ui4v qs0_0, qs0_1, qs0_2, qs0_3, qs1_0, qs1_1, qs1_2, qs1_3;
  { const ui4v* qr0 = (const ui4v*)(qtbl + (size_t)xrow[0] * 64) + qd4;
    qs0_0 = qr0[0]; qs0_1 = qr0[1]; qs0_2 = qr0[2]; qs0_3 = qr0[3];
    const ui4v* qr1 = (const ui4v*)(qtbl + (size_t)xrow[1] * 64) + qd4;
    qs1_0 = qr1[0]; qs1_1 = qr1[1]; qs1_2 = qr1[2]; qs1_3 = qr1[3]; }

  for (int t8 = 0; t8 < 512; ++t8) {
    int tbase = t8 * 8;
    STEP(0,0,2,0) STEP(1,1,3,1) STEP(2,2,0,0) STEP(3,3,1,1)
    STEP(4,0,2,0) STEP(5,1,3,1) STEP(6,2,0,0) STEP(7,3,1,1)
  }
  if (qdx == 0 && chain < NN) chainLL[chain] = LLacc;
}

// ---------- K4a: sum of Emax over all tokens ----------
__global__ __launch_bounds__(256) void k_emaxsum(const int* __restrict__ x,
    const float* __restrict__ Emax, float* __restrict__ sumE, int NT) {
  int idx = blockIdx.x * 256 + threadIdx.x;
  float s = 0.f;
  for (; idx < NT; idx += 128 * 256) s += Emax[x[idx]];
  #pragma unroll
  for (int mk = 1; mk < 64; mk <<= 1) s += __shfl_xor(s, mk, 64);
  if ((threadIdx.x & 63) == 0) atomicAdd(sumE, s);
}

// ---------- K4b: final scalar ----------
__global__ void k_final(const float* __restrict__ chainLL, const float* __restrict__ sumE,
                        float* __restrict__ out, int N) {
  int l = threadIdx.x;
  float v = (l < N) ? chainLL[l] : 0.f;
  #pragma unroll
  for (int mk = 1; mk < 64; mk <<= 1) v += __shfl_xor(v, mk, 64);
  if (l == 0) out[0] = -(v + sumE[0]) / (float)N;
}

extern "C" void kernel_launch(void* const* d_in, const int* in_sizes, int n_in,
                              void* d_out, int out_size, void* d_ws, size_t ws_size,
                              hipStream_t stream) {
  if (n_in < 6) return;
  const int*   x       = (const int*)d_in[0];
  const float* start_w = (const float*)d_in[1];
  const float* start_b = (const float*)d_in[2];
  const float* trans_w = (const float*)d_in[3];
  const float* emb_w   = (const float*)d_in[4];
  const float* vocab_w = (const float*)d_in[5];
  int NT = in_sizes[0];
  int N  = NT / 4096;
  int V  = in_sizes[5] / 128;

  char* ws = (char*)d_ws;
  float* S_glob  = (float*)(ws + 0);        // 128 f
  float* sumE    = (float*)(ws + 512);      // 1 f
  float* chainLL = (float*)(ws + 768);      // N f
  uint*  Atbl    = (uint*)(ws + 1024);      // 8192 dwords = 32 KB (MFMA A layout)
  float* Emax    = (float*)(ws + 36864);    // V floats
  uint*  qtbl    = (uint*)(ws + 262144);    // V*64 dwords = 12.8 MB (pair-linear)

  hipMemsetAsync(d_ws, 0, 1024, stream);
  k_tranA<<<dim3(1), dim3(128), 0, stream>>>(trans_w, Atbl);
  k_logits<<<dim3((V + 63) / 64), dim3(256), 0, stream>>>(emb_w, vocab_w, qtbl, S_glob, V);
  k_qtab<<<dim3((V + 3) / 4), dim3(256), 0, stream>>>(qtbl, S_glob, Emax, V);
  k_chain<<<dim3((N + 15) / 16), dim3(64), 0, stream>>>(x, start_w, start_b, Atbl, qtbl, chainLL, N);
  k_emaxsum<<<dim3(128), dim3(256), 0, stream>>>(x, Emax, sumE, NT);
  k_final<<<dim3(1), dim3(64), 0, stream>>>(chainLL, sumE, (float*)d_out, N);
}

// Round 8
// 1798.145 us; speedup vs baseline: 1.4532x; 1.4532x over previous
//
#include <hip/hip_runtime.h>

typedef unsigned int uint;
typedef uint4 uint4_a __attribute__((may_alias));
typedef uint ui4v __attribute__((ext_vector_type(4)));

// ---------- bf16 helpers ----------
__device__ __forceinline__ uint bfpack(float a, float b) {
  uint ua = __float_as_uint(a), ub = __float_as_uint(b);
  ua += 0x7fffu + ((ua >> 16) & 1u);   // RNE to bf16
  ub += 0x7fffu + ((ub >> 16) & 1u);
  return (ua >> 16) | (ub & 0xffff0000u);
}
__device__ __forceinline__ float bflo(uint d) { return __uint_as_float(d << 16); }
__device__ __forceinline__ float bfhi(uint d) { return __uint_as_float(d & 0xffff0000u); }

#if __has_builtin(__builtin_amdgcn_fdot2_f32_bf16)
#define HAVE_BFDOT 1
typedef __bf16 v2bf __attribute__((ext_vector_type(2)));
__device__ __forceinline__ float dot2bf(uint a, uint b, float c) {
  return __builtin_amdgcn_fdot2_f32_bf16(__builtin_bit_cast(v2bf, a),
                                         __builtin_bit_cast(v2bf, b), c, false);
}
#else
#define HAVE_BFDOT 0
#endif

// ---------- K1: transition table ----------
// Tcol[c*64 + j] = bf16x2( exp(tran[2j][c]), exp(tran[2j+1][c]) ), tran = log_softmax rows
__global__ void k_tran(const float* __restrict__ w, uint* __restrict__ Tcol) {
  __shared__ float rowLSE[128];
  int tid = threadIdx.x;                       // 128 threads
  const float4* w4 = (const float4*)(w + tid * 128);
  float se = 0.f;
  #pragma unroll 8
  for (int i = 0; i < 32; ++i) {
    float4 v = w4[i];
    se += __expf(v.x) + __expf(v.y) + __expf(v.z) + __expf(v.w);
  }
  rowLSE[tid] = __logf(se);                    // logits in (-1,1): shift-free LSE is fine
  __syncthreads();
  int c = tid;
  for (int j = 0; j < 64; ++j) {
    float a = __expf(w[(2 * j) * 128 + c]     - rowLSE[2 * j]);
    float b = __expf(w[(2 * j + 1) * 128 + c] - rowLSE[2 * j + 1]);
    Tcol[c * 64 + j] = bfpack(a, b);
  }
}

// ---------- K2a: logits (bf16, pair layout) + per-k sum of exp(logit) ----------
__global__ __launch_bounds__(256) void k_logits(const float* __restrict__ emb,
    const float* __restrict__ vocab, uint* __restrict__ qtbl,
    float* __restrict__ S_glob, int V) {
  __shared__ float S_part[128];
  int tid = threadIdx.x;
  int kt = tid & 15, vt = tid >> 4;
  int k0 = kt * 8;
  int vbase = blockIdx.x * 64 + vt * 4;
  if (tid < 128) S_part[tid] = 0.f;
  __syncthreads();

  float acc[4][8];
  #pragma unroll
  for (int i = 0; i < 4; ++i)
    #pragma unroll
    for (int r = 0; r < 8; ++r) acc[i][r] = 0.f;

  int vidx[4];
  #pragma unroll
  for (int i = 0; i < 4; ++i) { int vv = vbase + i; vidx[i] = (vv < V) ? vv : (V - 1); }

  const float4* emb4 = (const float4*)emb;
  const float4* voc4 = (const float4*)vocab;
  for (int jb = 0; jb < 32; ++jb) {
    float4 e4[8];
    #pragma unroll
    for (int r = 0; r < 8; ++r) e4[r] = emb4[(k0 + r) * 32 + jb];
    #pragma unroll
    for (int i = 0; i < 4; ++i) {
      float4 va = voc4[(size_t)vidx[i] * 32 + jb];
      #pragma unroll
      for (int r = 0; r < 8; ++r)
        acc[i][r] += va.x * e4[r].x + va.y * e4[r].y + va.z * e4[r].z + va.w * e4[r].w;
    }
  }

  float sume[8];
  #pragma unroll
  for (int r = 0; r < 8; ++r) sume[r] = 0.f;
  #pragma unroll
  for (int i = 0; i < 4; ++i) {
    int vv = vbase + i;
    if (vv < V) {
      #pragma unroll
      for (int r = 0; r < 8; ++r) sume[r] += __expf(acc[i][r]);   // |logit| <~ 40 : safe
      uint4 st;
      st.x = bfpack(acc[i][0], acc[i][1]);
      st.y = bfpack(acc[i][2], acc[i][3]);
      st.z = bfpack(acc[i][4], acc[i][5]);
      st.w = bfpack(acc[i][6], acc[i][7]);
      *((uint4*)(qtbl + (size_t)vv * 64) + kt) = st;
    }
  }
  #pragma unroll
  for (int r = 0; r < 8; ++r) atomicAdd(&S_part[k0 + r], sume[r]);
  __syncthreads();
  if (tid < 128) atomicAdd(&S_glob[tid], S_part[tid]);
}

// ---------- K2c: in-place q[v][k] = exp(emis - Emax_v) (bf16), Emax table ----------
__global__ __launch_bounds__(256) void k_qtab(uint* __restrict__ qtbl,
    const float* __restrict__ S_glob, float* __restrict__ Emax, int V) {
  int tid = threadIdx.x;
  int l = tid & 63;
  int v = blockIdx.x * 4 + (tid >> 6);
  if (v >= V) return;
  float2 S2 = ((const float2*)S_glob)[l];
  float z0 = __logf(S2.x), z1 = __logf(S2.y);
  size_t off = (size_t)v * 64 + l;
  uint d = qtbl[off];
  float e0 = bflo(d) - z0, e1 = bfhi(d) - z1;
  float m = fmaxf(e0, e1);
  #pragma unroll
  for (int s = 1; s < 64; s <<= 1) m = fmaxf(m, __shfl_xor(m, s, 64));
  float q0 = __expf(e0 - m), q1 = __expf(e1 - m);
  qtbl[off] = bfpack(q0, q1);
  if (l == 0) Emax[v] = m;
}

// ---------- K3: sequential scan. ONE wave per chain. ----------
// Lane l owns output states 2l,2l+1. T columns (128 dwords) PINNED IN AGPRs via "+a"
// (unified gfx950 RF; R7 proved this sticks at VGPR_Count=212 with zero scratch —
// the plain-VGPR variants R1/R3/R5/R6 all spilled). u broadcast via 16 ds_read_b128
// (same-address broadcast = conflict-free); same-wave DS ordering makes the
// write->read dependency safe without barriers.

#if HAVE_BFDOT
#define DOT_I(i) { uint4 uu = u4[i]; \
  A0 = dot2bf(uu.x, ta##i.x, A0); B0 = dot2bf(uu.x, tb##i.x, B0); \
  A1 = dot2bf(uu.y, ta##i.y, A1); B1 = dot2bf(uu.y, tb##i.y, B1); \
  A2 = dot2bf(uu.z, ta##i.z, A2); B2 = dot2bf(uu.z, tb##i.z, B2); \
  A3 = dot2bf(uu.w, ta##i.w, A3); B3 = dot2bf(uu.w, tb##i.w, B3); }
#else
#define DOT_I(i) { uint4 uu = u4[i]; \
  float x0 = bflo(uu.x), x1 = bfhi(uu.x), x2 = bflo(uu.y), x3 = bfhi(uu.y); \
  float x4 = bflo(uu.z), x5 = bfhi(uu.z), x6 = bflo(uu.w), x7 = bfhi(uu.w); \
  A0 = fmaf(x0, bflo(ta##i.x), A0); A0 = fmaf(x1, bfhi(ta##i.x), A0); \
  B0 = fmaf(x0, bflo(tb##i.x), B0); B0 = fmaf(x1, bfhi(tb##i.x), B0); \
  A1 = fmaf(x2, bflo(ta##i.y), A1); A1 = fmaf(x3, bfhi(ta##i.y), A1); \
  B1 = fmaf(x2, bflo(tb##i.y), B1); B1 = fmaf(x3, bfhi(tb##i.y), B1); \
  A2 = fmaf(x4, bflo(ta##i.z), A2); A2 = fmaf(x5, bfhi(ta##i.z), A2); \
  B2 = fmaf(x4, bflo(tb##i.z), B2); B2 = fmaf(x5, bfhi(tb##i.z), B2); \
  A3 = fmaf(x6, bflo(ta##i.w), A3); A3 = fmaf(x7, bfhi(ta##i.w), A3); \
  B3 = fmaf(x6, bflo(tb##i.w), B3); B3 = fmaf(x7, bfhi(tb##i.w), B3); }
#endif

#define REP16(M) M(0) M(1) M(2) M(3) M(4) M(5) M(6) M(7) \
                 M(8) M(9) M(10) M(11) M(12) M(13) M(14) M(15)

#define DECL_T(i) ui4v ta##i, tb##i;
#define LOAD_T(i) ta##i = ca[i]; tb##i = cb[i];
// AGPR pin: forces the table into the ACC half of the unified RF; no spill, no remat.
#define PIN_T(i)  asm volatile("" : "+a"(ta##i)); asm volatile("" : "+a"(tb##i));

#define STEP(j) { \
  float A0 = 0.f, A1 = 0.f, A2 = 0.f, A3 = 0.f; \
  float B0 = 0.f, B1 = 0.f, B2 = 0.f, B3 = 0.f; \
  REP16(DOT_I) \
  float s0 = (A0 + A1) + (A2 + A3); \
  float s1 = (B0 + B1) + (B2 + B3); \
  float nu0 = s0 * bflo(qc##j), nu1 = s1 * bfhi(qc##j); \
  { int tok = xs[(tbase + (j) + 8) & 4095]; qc##j = qtbl[(size_t)tok * 64 + l]; } \
  if ((j) == 7) {                                 /* exact renorm every 8 steps */ \
    float tt = nu0 + nu1; \
    for (int s = 1; s < 64; s <<= 1) tt += __shfl_xor(tt, s, 64); \
    LLacc += __logf(tt); \
    float it = 1.0f / tt; nu0 *= it; nu1 *= it; \
  } \
  u_mem[l] = bfpack(nu0, nu1); }                  /* same-wave DS order: no barrier */

__global__ __attribute__((amdgpu_flat_work_group_size(64, 64), amdgpu_waves_per_eu(1, 1)))
void k_chain(const int* __restrict__ x,
    const float* __restrict__ start_w, const float* __restrict__ start_b,
    const uint* __restrict__ Tcol, const uint* __restrict__ qtbl,
    float* __restrict__ chainLL) {
  __shared__ int xs[4096];
  __shared__ uint u_mem[64] __attribute__((aligned(16)));
  int n = blockIdx.x, l = threadIdx.x;
  const int* xrow = x + (size_t)n * 4096;
  #pragma unroll 4
  for (int i = l; i < 4096; i += 64) xs[i] = xrow[i];

  const ui4v* ca = (const ui4v*)(Tcol + (2 * l) * 64);
  const ui4v* cb = (const ui4v*)(Tcol + (2 * l + 1) * 64);
  REP16(DECL_T)
  REP16(LOAD_T)
  REP16(PIN_T)

  // init: u0 = softmax(start_w + start_b), LL0 = LSE(alpha0)
  float a0i = start_w[2 * l] + start_b[2 * l];
  float a1i = start_w[2 * l + 1] + start_b[2 * l + 1];
  float m = fmaxf(a0i, a1i);
  #pragma unroll
  for (int s = 1; s < 64; s <<= 1) m = fmaxf(m, __shfl_xor(m, s, 64));
  float p0 = __expf(a0i - m), p1 = __expf(a1i - m);
  float tot = p0 + p1;
  #pragma unroll
  for (int s = 1; s < 64; s <<= 1) tot += __shfl_xor(tot, s, 64);
  float LLacc = m + __logf(tot);
  float inv = 1.0f / tot;
  __syncthreads();
  u_mem[l] = bfpack(p0 * inv, p1 * inv);          // packed u(2l,2l+1)

  uint qc0 = qtbl[(size_t)xs[0] * 64 + l], qc1 = qtbl[(size_t)xs[1] * 64 + l];
  uint qc2 = qtbl[(size_t)xs[2] * 64 + l], qc3 = qtbl[(size_t)xs[3] * 64 + l];
  uint qc4 = qtbl[(size_t)xs[4] * 64 + l], qc5 = qtbl[(size_t)xs[5] * 64 + l];
  uint qc6 = qtbl[(size_t)xs[6] * 64 + l], qc7 = qtbl[(size_t)xs[7] * 64 + l];

  const uint4_a* u4 = (const uint4_a*)u_mem;
  for (int t8 = 0; t8 < 512; ++t8) {
    int tbase = t8 * 8;
    STEP(0) STEP(1) STEP(2) STEP(3) STEP(4) STEP(5) STEP(6) STEP(7)
  }
  if (l == 0) chainLL[n] = LLacc;
}

// ---------- K4a: sum of Emax over all tokens ----------
__global__ __launch_bounds__(256) void k_emaxsum(const int* __restrict__ x,
    const float* __restrict__ Emax, float* __restrict__ sumE, int NT) {
  int idx = blockIdx.x * 256 + threadIdx.x;
  float s = 0.f;
  for (; idx < NT; idx += 128 * 256) s += Emax[x[idx]];
  #pragma unroll
  for (int mk = 1; mk < 64; mk <<= 1) s += __shfl_xor(s, mk, 64);
  if ((threadIdx.x & 63) == 0) atomicAdd(sumE, s);
}

// ---------- K4b: final scalar ----------
__global__ void k_final(const float* __restrict__ chainLL, const float* __restrict__ sumE,
                        float* __restrict__ out, int N) {
  int l = threadIdx.x;
  float v = (l < N) ? chainLL[l] : 0.f;
  #pragma unroll
  for (int mk = 1; mk < 64; mk <<= 1) v += __shfl_xor(v, mk, 64);
  if (l == 0) out[0] = -(v + sumE[0]) / (float)N;
}

extern "C" void kernel_launch(void* const* d_in, const int* in_sizes, int n_in,
                              void* d_out, int out_size, void* d_ws, size_t ws_size,
                              hipStream_t stream) {
  if (n_in < 6) return;
  const int*   x       = (const int*)d_in[0];
  const float* start_w = (const float*)d_in[1];
  const float* start_b = (const float*)d_in[2];
  const float* trans_w = (const float*)d_in[3];
  const float* emb_w   = (const float*)d_in[4];
  const float* vocab_w = (const float*)d_in[5];
  int NT = in_sizes[0];
  int N  = NT / 4096;
  int V  = in_sizes[5] / 128;

  char* ws = (char*)d_ws;
  float* S_glob  = (float*)(ws + 0);        // 128 f
  float* sumE    = (float*)(ws + 512);      // 1 f
  float* chainLL = (float*)(ws + 768);      // N f
  uint*  Tcol    = (uint*)(ws + 1024);      // 128*64 dwords = 32 KB
  float* Emax    = (float*)(ws + 36864);    // V floats
  uint*  qtbl    = (uint*)(ws + 262144);    // V*64 dwords = 12.8 MB

  hipMemsetAsync(d_ws, 0, 1024, stream);
  k_tran<<<dim3(1), dim3(128), 0, stream>>>(trans_w, Tcol);
  k_logits<<<dim3((V + 63) / 64), dim3(256), 0, stream>>>(emb_w, vocab_w, qtbl, S_glob, V);
  k_qtab<<<dim3((V + 3) / 4), dim3(256), 0, stream>>>(qtbl, S_glob, Emax, V);
  k_chain<<<dim3(N), dim3(64), 0, stream>>>(x, start_w, start_b, Tcol, qtbl, chainLL);
  k_emaxsum<<<dim3(128), dim3(256), 0, stream>>>(x, Emax, sumE, NT);
  k_final<<<dim3(1), dim3(64), 0, stream>>>(chainLL, sumE, (float*)d_out, N);
}

// Round 9
// 1648.913 us; speedup vs baseline: 1.5847x; 1.0905x over previous
//
#include <hip/hip_runtime.h>

typedef unsigned int uint;

// ---------- bf16 helpers ----------
__device__ __forceinline__ uint bfpack(float a, float b) {
  uint ua = __float_as_uint(a), ub = __float_as_uint(b);
  ua += 0x7fffu + ((ua >> 16) & 1u);   // RNE to bf16
  ub += 0x7fffu + ((ub >> 16) & 1u);
  return (ua >> 16) | (ub & 0xffff0000u);
}
__device__ __forceinline__ float bflo(uint d) { return __uint_as_float(d << 16); }
__device__ __forceinline__ float bfhi(uint d) { return __uint_as_float(d & 0xffff0000u); }

#if __has_builtin(__builtin_amdgcn_fdot2_f32_bf16)
#define HAVE_BFDOT 1
typedef __bf16 v2bf __attribute__((ext_vector_type(2)));
__device__ __forceinline__ float dot2bf(uint a, uint b, float c) {
  return __builtin_amdgcn_fdot2_f32_bf16(__builtin_bit_cast(v2bf, a),
                                         __builtin_bit_cast(v2bf, b), c, false);
}
#else
#define HAVE_BFDOT 0
#endif

// ---------- K1: transition table ----------
// Tcol[c*64 + j] = bf16x2( exp(tran[2j][c]), exp(tran[2j+1][c]) ), tran = log_softmax rows
__global__ void k_tran(const float* __restrict__ w, uint* __restrict__ Tcol) {
  __shared__ float rowLSE[128];
  int tid = threadIdx.x;                       // 128 threads
  const float4* w4 = (const float4*)(w + tid * 128);
  float se = 0.f;
  #pragma unroll 8
  for (int i = 0; i < 32; ++i) {
    float4 v = w4[i];
    se += __expf(v.x) + __expf(v.y) + __expf(v.z) + __expf(v.w);
  }
  rowLSE[tid] = __logf(se);                    // logits in (-1,1): shift-free LSE is fine
  __syncthreads();
  int c = tid;
  for (int j = 0; j < 64; ++j) {
    float a = __expf(w[(2 * j) * 128 + c]     - rowLSE[2 * j]);
    float b = __expf(w[(2 * j + 1) * 128 + c] - rowLSE[2 * j + 1]);
    Tcol[c * 64 + j] = bfpack(a, b);
  }
}

// ---------- K2a: logits (bf16, pair layout) + per-k sum of exp(logit) ----------
__global__ __launch_bounds__(256) void k_logits(const float* __restrict__ emb,
    const float* __restrict__ vocab, uint* __restrict__ qtbl,
    float* __restrict__ S_glob, int V) {
  __shared__ float S_part[128];
  int tid = threadIdx.x;
  int kt = tid & 15, vt = tid >> 4;
  int k0 = kt * 8;
  int vbase = blockIdx.x * 64 + vt * 4;
  if (tid < 128) S_part[tid] = 0.f;
  __syncthreads();

  float acc[4][8];
  #pragma unroll
  for (int i = 0; i < 4; ++i)
    #pragma unroll
    for (int r = 0; r < 8; ++r) acc[i][r] = 0.f;

  int vidx[4];
  #pragma unroll
  for (int i = 0; i < 4; ++i) { int vv = vbase + i; vidx[i] = (vv < V) ? vv : (V - 1); }

  const float4* emb4 = (const float4*)emb;
  const float4* voc4 = (const float4*)vocab;
  for (int jb = 0; jb < 32; ++jb) {
    float4 e4[8];
    #pragma unroll
    for (int r = 0; r < 8; ++r) e4[r] = emb4[(k0 + r) * 32 + jb];
    #pragma unroll
    for (int i = 0; i < 4; ++i) {
      float4 va = voc4[(size_t)vidx[i] * 32 + jb];
      #pragma unroll
      for (int r = 0; r < 8; ++r)
        acc[i][r] += va.x * e4[r].x + va.y * e4[r].y + va.z * e4[r].z + va.w * e4[r].w;
    }
  }

  float sume[8];
  #pragma unroll
  for (int r = 0; r < 8; ++r) sume[r] = 0.f;
  #pragma unroll
  for (int i = 0; i < 4; ++i) {
    int vv = vbase + i;
    if (vv < V) {
      #pragma unroll
      for (int r = 0; r < 8; ++r) sume[r] += __expf(acc[i][r]);   // |logit| <~ 40 : safe
      uint4 st;
      st.x = bfpack(acc[i][0], acc[i][1]);
      st.y = bfpack(acc[i][2], acc[i][3]);
      st.z = bfpack(acc[i][4], acc[i][5]);
      st.w = bfpack(acc[i][6], acc[i][7]);
      *((uint4*)(qtbl + (size_t)vv * 64) + kt) = st;
    }
  }
  #pragma unroll
  for (int r = 0; r < 8; ++r) atomicAdd(&S_part[k0 + r], sume[r]);
  __syncthreads();
  if (tid < 128) atomicAdd(&S_glob[tid], S_part[tid]);
}

// ---------- K2c: in-place q[v][k] = exp(emis - Emax_v) (bf16), Emax table ----------
__global__ __launch_bounds__(256) void k_qtab(uint* __restrict__ qtbl,
    const float* __restrict__ S_glob, float* __restrict__ Emax, int V) {
  int tid = threadIdx.x;
  int l = tid & 63;
  int v = blockIdx.x * 4 + (tid >> 6);
  if (v >= V) return;
  float2 S2 = ((const float2*)S_glob)[l];
  float z0 = __logf(S2.x), z1 = __logf(S2.y);
  size_t off = (size_t)v * 64 + l;
  uint d = qtbl[off];
  float e0 = bflo(d) - z0, e1 = bfhi(d) - z1;
  float m = fmaxf(e0, e1);
  #pragma unroll
  for (int s = 1; s < 64; s <<= 1) m = fmaxf(m, __shfl_xor(m, s, 64));
  float q0 = __expf(e0 - m), q1 = __expf(e1 - m);
  qtbl[off] = bfpack(q0, q1);
  if (l == 0) Emax[v] = m;
}

// ---------- K3: sequential scan. 4 waves per chain, K split across waves. ----------
// R4 structure (proven 841 cyc/step) + the fix: TOKEN RING PREFETCH. R4 loaded
// tok from global and used it immediately as the qtbl prefetch address -> ~200cyc
// vmcnt stall every step ON the critical path. Now tk##j holds x[t+8], loaded a
// full superstep (8 steps) before its use, so neither load chain ever waits.

#define RLU(i) ((uint)__builtin_amdgcn_readlane((int)ud, rbase + (i)))

#if HAVE_BFDOT
#define DOTS \
  uint u0=RLU(0),u1=RLU(1),u2=RLU(2),u3=RLU(3),u4=RLU(4),u5=RLU(5),u6=RLU(6),u7=RLU(7), \
       u8=RLU(8),u9=RLU(9),u10=RLU(10),u11=RLU(11),u12=RLU(12),u13=RLU(13),u14=RLU(14),u15=RLU(15); \
  float A0 = dot2bf(u0, tA0.x, 0.f), A1 = dot2bf(u1, tA0.y, 0.f); \
  float A2 = dot2bf(u2, tA0.z, 0.f), A3 = dot2bf(u3, tA0.w, 0.f); \
  float B0 = dot2bf(u0, tB0.x, 0.f), B1 = dot2bf(u1, tB0.y, 0.f); \
  float B2 = dot2bf(u2, tB0.z, 0.f), B3 = dot2bf(u3, tB0.w, 0.f); \
  A0 = dot2bf(u4, tA1.x, A0); A1 = dot2bf(u5, tA1.y, A1); \
  A2 = dot2bf(u6, tA1.z, A2); A3 = dot2bf(u7, tA1.w, A3); \
  B0 = dot2bf(u4, tB1.x, B0); B1 = dot2bf(u5, tB1.y, B1); \
  B2 = dot2bf(u6, tB1.z, B2); B3 = dot2bf(u7, tB1.w, B3); \
  A0 = dot2bf(u8, tA2.x, A0); A1 = dot2bf(u9, tA2.y, A1); \
  A2 = dot2bf(u10, tA2.z, A2); A3 = dot2bf(u11, tA2.w, A3); \
  B0 = dot2bf(u8, tB2.x, B0); B1 = dot2bf(u9, tB2.y, B1); \
  B2 = dot2bf(u10, tB2.z, B2); B3 = dot2bf(u11, tB2.w, B3); \
  A0 = dot2bf(u12, tA3.x, A0); A1 = dot2bf(u13, tA3.y, A1); \
  A2 = dot2bf(u14, tA3.z, A2); A3 = dot2bf(u15, tA3.w, A3); \
  B0 = dot2bf(u12, tB3.x, B0); B1 = dot2bf(u13, tB3.y, B1); \
  B2 = dot2bf(u14, tB3.z, B2); B3 = dot2bf(u15, tB3.w, B3); \
  float Asum = (A0 + A1) + (A2 + A3), Bsum = (B0 + B1) + (B2 + B3);
#else
#define ACC2(i, AA, BB) { uint tu = RLU(i); float lo = bflo(tu), hi = bfhi(tu); \
  AA += lo * a##i.x; AA += hi * a##i.y; BB += lo * b##i.x; BB += hi * b##i.y; }
#define DOTS \
  float A0 = 0.f, A1 = 0.f, A2 = 0.f, A3 = 0.f; \
  float B0 = 0.f, B1 = 0.f, B2 = 0.f, B3 = 0.f; \
  ACC2(0, A0, B0) ACC2(1, A1, B1) ACC2(2, A2, B2) ACC2(3, A3, B3) \
  ACC2(4, A0, B0) ACC2(5, A1, B1) ACC2(6, A2, B2) ACC2(7, A3, B3) \
  ACC2(8, A0, B0) ACC2(9, A1, B1) ACC2(10, A2, B2) ACC2(11, A3, B3) \
  ACC2(12, A0, B0) ACC2(13, A1, B1) ACC2(14, A2, B2) ACC2(15, A3, B3) \
  float Asum = (A0 + A1) + (A2 + A3), Bsum = (B0 + B1) + (B2 + B3);
#endif

// p = literal 0/1 double-buffer selector. One raw barrier per step (lgkmcnt only:
// no vmcnt drain, so the q/token prefetch loads stay in flight across it).
#define STEP(j, p) { \
  DOTS \
  *(float2*)&partLDS[(p) * 640 + l * 10 + 2 * wv] = make_float2(Asum, Bsum); \
  asm volatile("s_waitcnt lgkmcnt(0)\ns_barrier" ::: "memory"); \
  const float2* pr = (const float2*)&partLDS[(p) * 640 + l * 10]; \
  float2 x0 = pr[0], x1 = pr[1], x2 = pr[2], x3 = pr[3]; \
  float s0 = (x0.x + x1.x) + (x2.x + x3.x); \
  float s1 = (x0.y + x1.y) + (x2.y + x3.y); \
  float nu0 = s0 * bflo(qc##j), nu1 = s1 * bfhi(qc##j); \
  qc##j = qtbl[(size_t)tk##j * 64 + l];          /* addr reg ready: no vmcnt wait */ \
  tk##j = xrow[(tbase + (j) + 16) & 4095];       /* token for NEXT superstep's prefetch */ \
  if ((j) == 7) {                                 /* exact renorm every 8 steps */ \
    float tt = nu0 + nu1; \
    for (int s = 1; s < 64; s <<= 1) tt += __shfl_xor(tt, s, 64); \
    LLacc += __logf(tt); \
    float it = 1.0f / tt; nu0 *= it; nu1 *= it; \
  } \
  ud = bfpack(nu0, nu1); }

__global__ __launch_bounds__(256, 1) void k_chain(const int* __restrict__ x,
    const float* __restrict__ start_w, const float* __restrict__ start_b,
    const uint* __restrict__ Tcol, const uint* __restrict__ qtbl,
    float* __restrict__ chainLL) {
  __shared__ float partLDS[1280];                 // [2][64 lanes x 10 dwords] = 5 KB
  int n = blockIdx.x;
  int l = threadIdx.x & 63;
  int wv = __builtin_amdgcn_readfirstlane((int)(threadIdx.x >> 6));  // force SGPR
  int rbase = wv * 16;
  const int* xrow = x + (size_t)n * 4096;

  // per-lane table fragment: columns 2l, 2l+1; input pairs [16wv, 16wv+16)
  const uint4* ca = (const uint4*)(Tcol + (2 * l) * 64 + rbase);
  const uint4* cb = (const uint4*)(Tcol + (2 * l + 1) * 64 + rbase);
  uint4 tA0 = ca[0], tA1 = ca[1], tA2 = ca[2], tA3 = ca[3];
  uint4 tB0 = cb[0], tB1 = cb[1], tB2 = cb[2], tB3 = cb[3];

#if !HAVE_BFDOT
  float2 a0 = make_float2(bflo(tA0.x), bfhi(tA0.x)), a1 = make_float2(bflo(tA0.y), bfhi(tA0.y));
  float2 a2 = make_float2(bflo(tA0.z), bfhi(tA0.z)), a3 = make_float2(bflo(tA0.w), bfhi(tA0.w));
  float2 a4 = make_float2(bflo(tA1.x), bfhi(tA1.x)), a5 = make_float2(bflo(tA1.y), bfhi(tA1.y));
  float2 a6 = make_float2(bflo(tA1.z), bfhi(tA1.z)), a7 = make_float2(bflo(tA1.w), bfhi(tA1.w));
  float2 a8 = make_float2(bflo(tA2.x), bfhi(tA2.x)), a9 = make_float2(bflo(tA2.y), bfhi(tA2.y));
  float2 a10 = make_float2(bflo(tA2.z), bfhi(tA2.z)), a11 = make_float2(bflo(tA2.w), bfhi(tA2.w));
  float2 a12 = make_float2(bflo(tA3.x), bfhi(tA3.x)), a13 = make_float2(bflo(tA3.y), bfhi(tA3.y));
  float2 a14 = make_float2(bflo(tA3.z), bfhi(tA3.z)), a15 = make_float2(bflo(tA3.w), bfhi(tA3.w));
  float2 b0 = make_float2(bflo(tB0.x), bfhi(tB0.x)), b1 = make_float2(bflo(tB0.y), bfhi(tB0.y));
  float2 b2 = make_float2(bflo(tB0.z), bfhi(tB0.z)), b3 = make_float2(bflo(tB0.w), bfhi(tB0.w));
  float2 b4 = make_float2(bflo(tB1.x), bfhi(tB1.x)), b5 = make_float2(bflo(tB1.y), bfhi(tB1.y));
  float2 b6 = make_float2(bflo(tB1.z), bfhi(tB1.z)), b7 = make_float2(bflo(tB1.w), bfhi(tB1.w));
  float2 b8 = make_float2(bflo(tB2.x), bfhi(tB2.x)), b9 = make_float2(bflo(tB2.y), bfhi(tB2.y));
  float2 b10 = make_float2(bflo(tB2.z), bfhi(tB2.z)), b11 = make_float2(bflo(tB2.w), bfhi(tB2.w));
  float2 b12 = make_float2(bflo(tB3.x), bfhi(tB3.x)), b13 = make_float2(bflo(tB3.y), bfhi(tB3.y));
  float2 b14 = make_float2(bflo(tB3.z), bfhi(tB3.z)), b15 = make_float2(bflo(tB3.w), bfhi(tB3.w));
#endif

  // init: u0 = softmax(start_w + start_b), LL0 = LSE(alpha0). Identical in all waves.
  float a0i = start_w[2 * l] + start_b[2 * l];
  float a1i = start_w[2 * l + 1] + start_b[2 * l + 1];
  float m = fmaxf(a0i, a1i);
  #pragma unroll
  for (int s = 1; s < 64; s <<= 1) m = fmaxf(m, __shfl_xor(m, s, 64));
  float p0 = __expf(a0i - m), p1 = __expf(a1i - m);
  float tot = p0 + p1;
  #pragma unroll
  for (int s = 1; s < 64; s <<= 1) tot += __shfl_xor(tot, s, 64);
  float LLacc = m + __logf(tot);
  float inv = 1.0f / tot;
  uint ud = bfpack(p0 * inv, p1 * inv);           // packed u(2l,2l+1), lives in a VGPR

  // q ring (8 ahead) + token ring (16 ahead -> q-prefetch address never waits)
  uint qc0 = qtbl[(size_t)xrow[0] * 64 + l], qc1 = qtbl[(size_t)xrow[1] * 64 + l];
  uint qc2 = qtbl[(size_t)xrow[2] * 64 + l], qc3 = qtbl[(size_t)xrow[3] * 64 + l];
  uint qc4 = qtbl[(size_t)xrow[4] * 64 + l], qc5 = qtbl[(size_t)xrow[5] * 64 + l];
  uint qc6 = qtbl[(size_t)xrow[6] * 64 + l], qc7 = qtbl[(size_t)xrow[7] * 64 + l];
  int tk0 = xrow[8],  tk1 = xrow[9],  tk2 = xrow[10], tk3 = xrow[11];
  int tk4 = xrow[12], tk5 = xrow[13], tk6 = xrow[14], tk7 = xrow[15];

  for (int t8 = 0; t8 < 512; ++t8) {
    int tbase = t8 * 8;
    STEP(0, 0) STEP(1, 1) STEP(2, 0) STEP(3, 1)
    STEP(4, 0) STEP(5, 1) STEP(6, 0) STEP(7, 1)
  }
  if (l == 0 && wv == 0) chainLL[n] = LLacc;
}

// ---------- K4a: sum of Emax over all tokens ----------
__global__ __launch_bounds__(256) void k_emaxsum(const int* __restrict__ x,
    const float* __restrict__ Emax, float* __restrict__ sumE, int NT) {
  int idx = blockIdx.x * 256 + threadIdx.x;
  float s = 0.f;
  for (; idx < NT; idx += 128 * 256) s += Emax[x[idx]];
  #pragma unroll
  for (int mk = 1; mk < 64; mk <<= 1) s += __shfl_xor(s, mk, 64);
  if ((threadIdx.x & 63) == 0) atomicAdd(sumE, s);
}

// ---------- K4b: final scalar ----------
__global__ void k_final(const float* __restrict__ chainLL, const float* __restrict__ sumE,
                        float* __restrict__ out, int N) {
  int l = threadIdx.x;
  float v = (l < N) ? chainLL[l] : 0.f;
  #pragma unroll
  for (int mk = 1; mk < 64; mk <<= 1) v += __shfl_xor(v, mk, 64);
  if (l == 0) out[0] = -(v + sumE[0]) / (float)N;
}

extern "C" void kernel_launch(void* const* d_in, const int* in_sizes, int n_in,
                              void* d_out, int out_size, void* d_ws, size_t ws_size,
                              hipStream_t stream) {
  if (n_in < 6) return;
  const int*   x       = (const int*)d_in[0];
  const float* start_w = (const float*)d_in[1];
  const float* start_b = (const float*)d_in[2];
  const float* trans_w = (const float*)d_in[3];
  const float* emb_w   = (const float*)d_in[4];
  const float* vocab_w = (const float*)d_in[5];
  int NT = in_sizes[0];
  int N  = NT / 4096;
  int V  = in_sizes[5] / 128;

  char* ws = (char*)d_ws;
  float* S_glob  = (float*)(ws + 0);        // 128 f
  float* sumE    = (float*)(ws + 512);      // 1 f
  float* chainLL = (float*)(ws + 768);      // N f
  uint*  Tcol    = (uint*)(ws + 1024);      // 128*64 dwords = 32 KB
  float* Emax    = (float*)(ws + 36864);    // V floats
  uint*  qtbl    = (uint*)(ws + 262144);    // V*64 dwords = 12.8 MB

  hipMemsetAsync(d_ws, 0, 1024, stream);
  k_tran<<<dim3(1), dim3(128), 0, stream>>>(trans_w, Tcol);
  k_logits<<<dim3((V + 63) / 64), dim3(256), 0, stream>>>(emb_w, vocab_w, qtbl, S_glob, V);
  k_qtab<<<dim3((V + 3) / 4), dim3(256), 0, stream>>>(qtbl, S_glob, Emax, V);
  k_chain<<<dim3(N), dim3(256), 0, stream>>>(x, start_w, start_b, Tcol, qtbl, chainLL);
  k_emaxsum<<<dim3(128), dim3(256), 0, stream>>>(x, Emax, sumE, NT);
  k_final<<<dim3(1), dim3(64), 0, stream>>>(chainLL, sumE, (float*)d_out, N);
}

// Round 10
// 1116.931 us; speedup vs baseline: 2.3395x; 1.4763x over previous
//
#include <hip/hip_runtime.h>

typedef unsigned int uint;
typedef unsigned short ushort;
typedef uint4 uint4_a __attribute__((may_alias));
typedef uint ui4v __attribute__((ext_vector_type(4)));
typedef float fx4 __attribute__((ext_vector_type(4)));
typedef short s8v __attribute__((ext_vector_type(8)));

// ---------- bf16 helpers ----------
__device__ __forceinline__ uint bfpack(float a, float b) {
  uint ua = __float_as_uint(a), ub = __float_as_uint(b);
  ua += 0x7fffu + ((ua >> 16) & 1u);   // RNE
  ub += 0x7fffu + ((ub >> 16) & 1u);
  return (ua >> 16) | (ub & 0xffff0000u);
}
__device__ __forceinline__ float bflo(uint d) { return __uint_as_float(d << 16); }
__device__ __forceinline__ float bfhi(uint d) { return __uint_as_float(d & 0xffff0000u); }
__device__ __forceinline__ ushort bfr(float s) {          // round-half-up f32->bf16
  return (ushort)((__float_as_uint(s) + 0x8000u) >> 16);
}

#if __has_builtin(__builtin_amdgcn_fdot2_f32_bf16)
#define HAVE_BFDOT 1
typedef __bf16 v2bf __attribute__((ext_vector_type(2)));
__device__ __forceinline__ float dot2bf(uint a, uint b, float c) {
  return __builtin_amdgcn_fdot2_f32_bf16(__builtin_bit_cast(v2bf, a),
                                         __builtin_bit_cast(v2bf, b), c, false);
}
#else
#define HAVE_BFDOT 0
#endif

// ---------- K1: transition table, column-pair layout ----------
// Tcol[c*64 + kp] = bf16x2( exp(tran[2kp][c]), exp(tran[2kp+1][c]) )
__global__ void k_tran(const float* __restrict__ w, uint* __restrict__ Tcol) {
  __shared__ float rowLSE[128];
  int tid = threadIdx.x;                       // 128 threads
  const float4* w4 = (const float4*)(w + tid * 128);
  float se = 0.f;
  #pragma unroll 8
  for (int i = 0; i < 32; ++i) {
    float4 v = w4[i];
    se += __expf(v.x) + __expf(v.y) + __expf(v.z) + __expf(v.w);
  }
  rowLSE[tid] = __logf(se);
  __syncthreads();
  int c = tid;
  for (int j = 0; j < 64; ++j) {
    float a = __expf(w[(2 * j) * 128 + c]     - rowLSE[2 * j]);
    float b = __expf(w[(2 * j + 1) * 128 + c] - rowLSE[2 * j + 1]);
    Tcol[c * 64 + j] = bfpack(a, b);
  }
}

// ---------- K2a: logits (bf16, pair layout) + per-k sum of exp(logit) ----------
__global__ __launch_bounds__(256) void k_logits(const float* __restrict__ emb,
    const float* __restrict__ vocab, uint* __restrict__ qtbl,
    float* __restrict__ S_glob, int V) {
  __shared__ float S_part[128];
  int tid = threadIdx.x;
  int kt = tid & 15, vt = tid >> 4;
  int k0 = kt * 8;
  int vbase = blockIdx.x * 64 + vt * 4;
  if (tid < 128) S_part[tid] = 0.f;
  __syncthreads();

  float acc[4][8];
  #pragma unroll
  for (int i = 0; i < 4; ++i)
    #pragma unroll
    for (int r = 0; r < 8; ++r) acc[i][r] = 0.f;

  int vidx[4];
  #pragma unroll
  for (int i = 0; i < 4; ++i) { int vv = vbase + i; vidx[i] = (vv < V) ? vv : (V - 1); }

  const float4* emb4 = (const float4*)emb;
  const float4* voc4 = (const float4*)vocab;
  for (int jb = 0; jb < 32; ++jb) {
    float4 e4[8];
    #pragma unroll
    for (int r = 0; r < 8; ++r) e4[r] = emb4[(k0 + r) * 32 + jb];
    #pragma unroll
    for (int i = 0; i < 4; ++i) {
      float4 va = voc4[(size_t)vidx[i] * 32 + jb];
      #pragma unroll
      for (int r = 0; r < 8; ++r)
        acc[i][r] += va.x * e4[r].x + va.y * e4[r].y + va.z * e4[r].z + va.w * e4[r].w;
    }
  }

  float sume[8];
  #pragma unroll
  for (int r = 0; r < 8; ++r) sume[r] = 0.f;
  #pragma unroll
  for (int i = 0; i < 4; ++i) {
    int vv = vbase + i;
    if (vv < V) {
      #pragma unroll
      for (int r = 0; r < 8; ++r) sume[r] += __expf(acc[i][r]);
      uint4 st;
      st.x = bfpack(acc[i][0], acc[i][1]);
      st.y = bfpack(acc[i][2], acc[i][3]);
      st.z = bfpack(acc[i][4], acc[i][5]);
      st.w = bfpack(acc[i][6], acc[i][7]);
      *((uint4*)(qtbl + (size_t)vv * 64) + kt) = st;
    }
  }
  #pragma unroll
  for (int r = 0; r < 8; ++r) atomicAdd(&S_part[k0 + r], sume[r]);
  __syncthreads();
  if (tid < 128) atomicAdd(&S_glob[tid], S_part[tid]);
}

// ---------- K2c: in-place q[v][k] = exp(emis - Emax_v) (bf16), Emax table ----------
__global__ __launch_bounds__(256) void k_qtab(uint* __restrict__ qtbl,
    const float* __restrict__ S_glob, float* __restrict__ Emax, int V) {
  int tid = threadIdx.x;
  int l = tid & 63;
  int v = blockIdx.x * 4 + (tid >> 6);
  if (v >= V) return;
  float2 S2 = ((const float2*)S_glob)[l];
  float z0 = __logf(S2.x), z1 = __logf(S2.y);
  size_t off = (size_t)v * 64 + l;
  uint d = qtbl[off];
  float e0 = bflo(d) - z0, e1 = bfhi(d) - z1;
  float m = fmaxf(e0, e1);
  #pragma unroll
  for (int s = 1; s < 64; s <<= 1) m = fmaxf(m, __shfl_xor(m, s, 64));
  float q0 = __expf(e0 - m), q1 = __expf(e1 - m);
  qtbl[off] = bfpack(q0, q1);
  if (l == 0) Emax[v] = m;
}

// =====================================================================
// PHASE 1: per (chain,segment) compute P_seg = prod_{t in seg} (T D_t)
// via MFMA folds R <- (R x T) D_t.  One workgroup (4 waves) per segment.
// Wave wv owns rows [32wv, 32wv+32).  T B-fragments static in AGPRs.
// R in LDS (bf16, row stride 70 dwords), double-buffered; 1 barrier/fold.
// Rescale by lagged block-max each fold; log of applied scales -> LLseg.
// =====================================================================
#define PSTRIDE 70

#define REP8S(M) M(0) M(1) M(2) M(3) M(4) M(5) M(6) M(7)
#define REPB(M) M(0,0) M(0,1) M(0,2) M(0,3) M(1,0) M(1,1) M(1,2) M(1,3) \
                M(2,0) M(2,1) M(2,2) M(2,3) M(3,0) M(3,1) M(3,2) M(3,3) \
                M(4,0) M(4,1) M(4,2) M(4,3) M(5,0) M(5,1) M(5,2) M(5,3) \
                M(6,0) M(6,1) M(6,2) M(6,3) M(7,0) M(7,1) M(7,2) M(7,3)

#define MF16(a, b, cacc) cacc = __builtin_amdgcn_mfma_f32_16x16x32_bf16( \
    __builtin_bit_cast(s8v, a), __builtin_bit_cast(s8v, b), cacc, 0, 0, 0);

#define LOADA(dst, mrow, ks, P) { \
  const uint2* ap_ = (const uint2*)&RL[P][(mrow) * PSTRIDE + 16 * (ks) + 4 * quad]; \
  uint2 lo_ = ap_[0], hi_ = ap_[1]; \
  dst.x = lo_.x; dst.y = lo_.y; dst.z = hi_.x; dst.w = hi_.y; }

#define KSGRP(ks) \
  MF16(aa##ks, tb0_##ks, cc00) MF16(aa##ks, tb1_##ks, cc01) \
  MF16(aa##ks, tb2_##ks, cc02) MF16(aa##ks, tb3_##ks, cc03) \
  MF16(aa##ks, tb4_##ks, cc04) MF16(aa##ks, tb5_##ks, cc05) \
  MF16(aa##ks, tb6_##ks, cc06) MF16(aa##ks, tb7_##ks, cc07) \
  MF16(ab##ks, tb0_##ks, cc10) MF16(ab##ks, tb1_##ks, cc11) \
  MF16(ab##ks, tb2_##ks, cc12) MF16(ab##ks, tb3_##ks, cc13) \
  MF16(ab##ks, tb4_##ks, cc14) MF16(ab##ks, tb5_##ks, cc15) \
  MF16(ab##ks, tb6_##ks, cc16) MF16(ab##ks, tb7_##ks, cc17)

#define EPI(mt, nt, WB) { \
  float s0 = cc##mt##nt.x * qs##nt, s1 = cc##mt##nt.y * qs##nt; \
  float s2 = cc##mt##nt.z * qs##nt, s3 = cc##mt##nt.w * qs##nt; \
  fm = fmaxf(fm, fmaxf(fmaxf(s0, s1), fmaxf(s2, s3))); \
  ushort* wp_ = (ushort*)&RL[WB][0]; \
  int r0_ = 32 * wv + 16 * (mt) + 4 * quad; \
  int ch_ = 16 * (nt) + c; \
  wp_[(r0_ + 0) * 140 + ch_] = bfr(s0); \
  wp_[(r0_ + 1) * 140 + ch_] = bfr(s1); \
  wp_[(r0_ + 2) * 140 + ch_] = bfr(s2); \
  wp_[(r0_ + 3) * 140 + ch_] = bfr(s3); }

#define REPEPI(WB) EPI(0,0,WB) EPI(0,1,WB) EPI(0,2,WB) EPI(0,3,WB) \
                   EPI(0,4,WB) EPI(0,5,WB) EPI(0,6,WB) EPI(0,7,WB) \
                   EPI(1,0,WB) EPI(1,1,WB) EPI(1,2,WB) EPI(1,3,WB) \
                   EPI(1,4,WB) EPI(1,5,WB) EPI(1,6,WB) EPI(1,7,WB)

#define FOLDBODY(P, WB, Q, TKREG, FBASE) { \
  float m0_ = wmaxs[WB][0], m1_ = wmaxs[WB][1], m2_ = wmaxs[WB][2], m3_ = wmaxs[WB][3]; \
  float fmx_ = fmaxf(fmaxf(m0_, m1_), fmaxf(m2_, m3_)); \
  rs = 1.0f / fmx_;  llacc += __logf(fmx_); \
  fx4 cc00 = zz4, cc01 = zz4, cc02 = zz4, cc03 = zz4; \
  fx4 cc04 = zz4, cc05 = zz4, cc06 = zz4, cc07 = zz4; \
  fx4 cc10 = zz4, cc11 = zz4, cc12 = zz4, cc13 = zz4; \
  fx4 cc14 = zz4, cc15 = zz4, cc16 = zz4, cc17 = zz4; \
  ui4v aa0, aa1, aa2, aa3, ab0, ab1, ab2, ab3; \
  LOADA(aa0, mb0, 0, P) LOADA(aa1, mb0, 1, P) LOADA(aa2, mb0, 2, P) LOADA(aa3, mb0, 3, P) \
  LOADA(ab0, mb1, 0, P) LOADA(ab1, mb1, 1, P) LOADA(ab2, mb1, 2, P) LOADA(ab3, mb1, 3, P) \
  KSGRP(0) KSGRP(1) KSGRP(2) KSGRP(3) \
  float qs0 = ((c & 1) ? bfhi(Q##0) : bflo(Q##0)) * rs; \
  float qs1 = ((c & 1) ? bfhi(Q##1) : bflo(Q##1)) * rs; \
  float qs2 = ((c & 1) ? bfhi(Q##2) : bflo(Q##2)) * rs; \
  float qs3 = ((c & 1) ? bfhi(Q##3) : bflo(Q##3)) * rs; \
  float qs4 = ((c & 1) ? bfhi(Q##4) : bflo(Q##4)) * rs; \
  float qs5 = ((c & 1) ? bfhi(Q##5) : bflo(Q##5)) * rs; \
  float qs6 = ((c & 1) ? bfhi(Q##6) : bflo(Q##6)) * rs; \
  float qs7 = ((c & 1) ? bfhi(Q##7) : bflo(Q##7)) * rs; \
  Q##0 = qtbl[(size_t)TKREG * 64 +  0 + (c >> 1)]; \
  Q##1 = qtbl[(size_t)TKREG * 64 +  8 + (c >> 1)]; \
  Q##2 = qtbl[(size_t)TKREG * 64 + 16 + (c >> 1)]; \
  Q##3 = qtbl[(size_t)TKREG * 64 + 24 + (c >> 1)]; \
  Q##4 = qtbl[(size_t)TKREG * 64 + 32 + (c >> 1)]; \
  Q##5 = qtbl[(size_t)TKREG * 64 + 40 + (c >> 1)]; \
  Q##6 = qtbl[(size_t)TKREG * 64 + 48 + (c >> 1)]; \
  Q##7 = qtbl[(size_t)TKREG * 64 + 56 + (c >> 1)]; \
  { int fi_ = (FBASE) + 4; if (fi_ > 511) fi_ = 511; TKREG = xseg[fi_]; } \
  float fm = 0.f; \
  REPEPI(WB) \
  fm = fmaxf(fm, __shfl_xor(fm, 1, 64));  fm = fmaxf(fm, __shfl_xor(fm, 2, 64)); \
  fm = fmaxf(fm, __shfl_xor(fm, 4, 64));  fm = fmaxf(fm, __shfl_xor(fm, 8, 64)); \
  fm = fmaxf(fm, __shfl_xor(fm, 16, 64)); fm = fmaxf(fm, __shfl_xor(fm, 32, 64)); \
  if (l == 0) wmaxs[P][wv] = fm; \
  asm volatile("s_waitcnt lgkmcnt(0)\ns_barrier" ::: "memory"); \
}

__global__ __attribute__((amdgpu_flat_work_group_size(256, 256), amdgpu_waves_per_eu(1, 1)))
void k_seg(const int* __restrict__ x, const uint* __restrict__ Tcol,
           const uint* __restrict__ qtbl, uint* __restrict__ Pst,
           float* __restrict__ LLseg) {
  __shared__ uint RL[2][128 * PSTRIDE];     // 70 KB
  __shared__ float wmaxs[2][4];
  int tid = threadIdx.x;
  int wv = tid >> 6, l = tid & 63, c = l & 15, quad = l >> 4;
  int blk = blockIdx.x;
  const int* xseg = x + (size_t)(blk >> 3) * 4096 + (size_t)(blk & 7) * 512;

  // static T B-fragments -> AGPRs.  frag(nt,ks): b128 at Tcol[(16nt+c)*64 + 16ks + 4quad]
  #define DECLB(nt, ks) ui4v tb##nt##_##ks;
  REPB(DECLB)
  {
    const ui4v* tp = (const ui4v*)Tcol;
    #define LOADB(nt, ks) tb##nt##_##ks = tp[(16 * (nt) + c) * 16 + 4 * (ks) + quad];
    REPB(LOADB)
    #define PINB(nt, ks) asm volatile("" : "+a"(tb##nt##_##ks));
    REPB(PINB)
  }

  // init R[0] = I, wmaxs = 1
  for (int i = tid; i < 128 * PSTRIDE; i += 256) RL[0][i] = 0;
  if (tid < 8) ((float*)wmaxs)[tid] = 1.0f;
  __syncthreads();
  if (tid < 128) RL[0][tid * PSTRIDE + (tid >> 1)] = 0x3F80u << (16 * (tid & 1));
  __syncthreads();

  int mb0 = 32 * wv + c, mb1 = mb0 + 16;
  float rs = 1.0f, llacc = 0.0f;
  fx4 zz4; zz4.x = 0.f; zz4.y = 0.f; zz4.z = 0.f; zz4.w = 0.f;

  int tk0 = xseg[0], tk1 = xseg[1];
  int tkA = xseg[2], tkB = xseg[3];
  #define QINITC(i) uint qc##i = qtbl[(size_t)tk0 * 64 + 8 * (i) + (c >> 1)];
  REP8S(QINITC)
  #define QINITN(i) uint qn##i = qtbl[(size_t)tk1 * 64 + 8 * (i) + (c >> 1)];
  REP8S(QINITN)

  for (int f2 = 0; f2 < 256; ++f2) {
    int f = f2 * 2;
    FOLDBODY(0, 1, qc, tkA, f)
    FOLDBODY(1, 0, qn, tkB, f + 1)
  }

  // final R is in RL[0] (fold 511 wrote buffer 0); copy to Pst col-pair layout
  for (int i = tid; i < 8192; i += 256) {
    int k = i >> 6, p = i & 63;
    Pst[(size_t)blk * 8192 + i] = RL[0][k * PSTRIDE + p];
  }
  if (tid == 0) LLseg[blk] = llacc;
}

// =====================================================================
// PHASE 2: per chain, alpha0 -> fold 8 segment matrices, accumulate LL
// =====================================================================
__global__ __launch_bounds__(64, 1) void k_comb(
    const float* __restrict__ start_w, const float* __restrict__ start_b,
    const uint* __restrict__ Pst, const float* __restrict__ LLseg,
    float* __restrict__ chainLL) {
  __shared__ uint al[64] __attribute__((aligned(16)));
  int n = blockIdx.x, l = threadIdx.x;
  float a0i = start_w[2 * l] + start_b[2 * l];
  float a1i = start_w[2 * l + 1] + start_b[2 * l + 1];
  float m = fmaxf(a0i, a1i);
  #pragma unroll
  for (int s = 1; s < 64; s <<= 1) m = fmaxf(m, __shfl_xor(m, s, 64));
  float p0 = __expf(a0i - m), p1 = __expf(a1i - m);
  float tot = p0 + p1;
  #pragma unroll
  for (int s = 1; s < 64; s <<= 1) tot += __shfl_xor(tot, s, 64);
  float LLacc = m + __logf(tot);
  float inv = 1.0f / tot;
  al[l] = bfpack(p0 * inv, p1 * inv);
  const uint4_a* u4 = (const uint4_a*)al;

  for (int s = 0; s < 8; ++s) {
    const uint* pb = Pst + (size_t)(n * 8 + s) * 8192;
    float o0 = 0.f, o1 = 0.f;
    #pragma unroll
    for (int i = 0; i < 16; ++i) {
      uint4 uu = u4[i];
      #pragma unroll
      for (int d = 0; d < 4; ++d) {
        uint ad = (d == 0) ? uu.x : (d == 1) ? uu.y : (d == 2) ? uu.z : uu.w;
        uint P0 = pb[(8 * i + 2 * d) * 64 + l];
        uint P1 = pb[(8 * i + 2 * d + 1) * 64 + l];
        float alo = bflo(ad), ahi = bfhi(ad);
        o0 = fmaf(alo, bflo(P0), o0); o0 = fmaf(ahi, bflo(P1), o0);
        o1 = fmaf(alo, bfhi(P0), o1); o1 = fmaf(ahi, bfhi(P1), o1);
      }
    }
    float tt = o0 + o1;
    #pragma unroll
    for (int sh = 1; sh < 64; sh <<= 1) tt += __shfl_xor(tt, sh, 64);
    LLacc += __logf(tt) + LLseg[n * 8 + s];
    float it = 1.0f / tt;
    al[l] = bfpack(o0 * it, o1 * it);       // same-wave LDS order: no barrier
  }
  if (l == 0) chainLL[n] = LLacc;
}

// =====================================================================
// FALLBACK (R9): sequential scan, 4 waves per chain — used if ws too small
// =====================================================================
#define RLU(i) ((uint)__builtin_amdgcn_readlane((int)ud, rbase + (i)))
#if HAVE_BFDOT
#define DOTS \
  uint u0=RLU(0),u1=RLU(1),u2=RLU(2),u3=RLU(3),u4=RLU(4),u5=RLU(5),u6=RLU(6),u7=RLU(7), \
       u8=RLU(8),u9=RLU(9),u10=RLU(10),u11=RLU(11),u12=RLU(12),u13=RLU(13),u14=RLU(14),u15=RLU(15); \
  float A0 = dot2bf(u0, tA0.x, 0.f), A1 = dot2bf(u1, tA0.y, 0.f); \
  float A2 = dot2bf(u2, tA0.z, 0.f), A3 = dot2bf(u3, tA0.w, 0.f); \
  float B0 = dot2bf(u0, tB0.x, 0.f), B1 = dot2bf(u1, tB0.y, 0.f); \
  float B2 = dot2bf(u2, tB0.z, 0.f), B3 = dot2bf(u3, tB0.w, 0.f); \
  A0 = dot2bf(u4, tA1.x, A0); A1 = dot2bf(u5, tA1.y, A1); \
  A2 = dot2bf(u6, tA1.z, A2); A3 = dot2bf(u7, tA1.w, A3); \
  B0 = dot2bf(u4, tB1.x, B0); B1 = dot2bf(u5, tB1.y, B1); \
  B2 = dot2bf(u6, tB1.z, B2); B3 = dot2bf(u7, tB1.w, B3); \
  A0 = dot2bf(u8, tA2.x, A0); A1 = dot2bf(u9, tA2.y, A1); \
  A2 = dot2bf(u10, tA2.z, A2); A3 = dot2bf(u11, tA2.w, A3); \
  B0 = dot2bf(u8, tB2.x, B0); B1 = dot2bf(u9, tB2.y, B1); \
  B2 = dot2bf(u10, tB2.z, B2); B3 = dot2bf(u11, tB2.w, B3); \
  A0 = dot2bf(u12, tA3.x, A0); A1 = dot2bf(u13, tA3.y, A1); \
  A2 = dot2bf(u14, tA3.z, A2); A3 = dot2bf(u15, tA3.w, A3); \
  B0 = dot2bf(u12, tB3.x, B0); B1 = dot2bf(u13, tB3.y, B1); \
  B2 = dot2bf(u14, tB3.z, B2); B3 = dot2bf(u15, tB3.w, B3); \
  float Asum = (A0 + A1) + (A2 + A3), Bsum = (B0 + B1) + (B2 + B3);
#else
#define ACC2(i, AA, BB) { uint tu = RLU(i); float lo = bflo(tu), hi = bfhi(tu); \
  AA += lo * fa##i.x; AA += hi * fa##i.y; BB += lo * fb##i.x; BB += hi * fb##i.y; }
#define DOTS \
  float A0 = 0.f, A1 = 0.f, A2 = 0.f, A3 = 0.f; \
  float B0 = 0.f, B1 = 0.f, B2 = 0.f, B3 = 0.f; \
  ACC2(0, A0, B0) ACC2(1, A1, B1) ACC2(2, A2, B2) ACC2(3, A3, B3) \
  ACC2(4, A0, B0) ACC2(5, A1, B1) ACC2(6, A2, B2) ACC2(7, A3, B3) \
  ACC2(8, A0, B0) ACC2(9, A1, B1) ACC2(10, A2, B2) ACC2(11, A3, B3) \
  ACC2(12, A0, B0) ACC2(13, A1, B1) ACC2(14, A2, B2) ACC2(15, A3, B3) \
  float Asum = (A0 + A1) + (A2 + A3), Bsum = (B0 + B1) + (B2 + B3);
#endif

#define STEPF(j, p) { \
  DOTS \
  *(float2*)&partLDS[(p) * 640 + l * 10 + 2 * wv] = make_float2(Asum, Bsum); \
  asm volatile("s_waitcnt lgkmcnt(0)\ns_barrier" ::: "memory"); \
  const float2* pr = (const float2*)&partLDS[(p) * 640 + l * 10]; \
  float2 x0 = pr[0], x1 = pr[1], x2 = pr[2], x3 = pr[3]; \
  float s0 = (x0.x + x1.x) + (x2.x + x3.x); \
  float s1 = (x0.y + x1.y) + (x2.y + x3.y); \
  float nu0 = s0 * bflo(qc##j), nu1 = s1 * bfhi(qc##j); \
  qc##j = qtbl[(size_t)tk##j * 64 + l]; \
  tk##j = xrow[(tbase + (j) + 16) & 4095]; \
  if ((j) == 7) { \
    float tt = nu0 + nu1; \
    for (int s = 1; s < 64; s <<= 1) tt += __shfl_xor(tt, s, 64); \
    LLacc += __logf(tt); \
    float it = 1.0f / tt; nu0 *= it; nu1 *= it; \
  } \
  ud = bfpack(nu0, nu1); }

__global__ __launch_bounds__(256, 1) void k_chain(const int* __restrict__ x,
    const float* __restrict__ start_w, const float* __restrict__ start_b,
    const uint* __restrict__ Tcol, const uint* __restrict__ qtbl,
    float* __restrict__ chainLL) {
  __shared__ float partLDS[1280];
  int n = blockIdx.x;
  int l = threadIdx.x & 63;
  int wv = __builtin_amdgcn_readfirstlane((int)(threadIdx.x >> 6));
  int rbase = wv * 16;
  const int* xrow = x + (size_t)n * 4096;

  const uint4* ca = (const uint4*)(Tcol + (2 * l) * 64 + rbase);
  const uint4* cb = (const uint4*)(Tcol + (2 * l + 1) * 64 + rbase);
  uint4 tA0 = ca[0], tA1 = ca[1], tA2 = ca[2], tA3 = ca[3];
  uint4 tB0 = cb[0], tB1 = cb[1], tB2 = cb[2], tB3 = cb[3];
#if !HAVE_BFDOT
  float2 fa0 = make_float2(bflo(tA0.x), bfhi(tA0.x)), fa1 = make_float2(bflo(tA0.y), bfhi(tA0.y));
  float2 fa2 = make_float2(bflo(tA0.z), bfhi(tA0.z)), fa3 = make_float2(bflo(tA0.w), bfhi(tA0.w));
  float2 fa4 = make_float2(bflo(tA1.x), bfhi(tA1.x)), fa5 = make_float2(bflo(tA1.y), bfhi(tA1.y));
  float2 fa6 = make_float2(bflo(tA1.z), bfhi(tA1.z)), fa7 = make_float2(bflo(tA1.w), bfhi(tA1.w));
  float2 fa8 = make_float2(bflo(tA2.x), bfhi(tA2.x)), fa9 = make_float2(bflo(tA2.y), bfhi(tA2.y));
  float2 fa10 = make_float2(bflo(tA2.z), bfhi(tA2.z)), fa11 = make_float2(bflo(tA2.w), bfhi(tA2.w));
  float2 fa12 = make_float2(bflo(tA3.x), bfhi(tA3.x)), fa13 = make_float2(bflo(tA3.y), bfhi(tA3.y));
  float2 fa14 = make_float2(bflo(tA3.z), bfhi(tA3.z)), fa15 = make_float2(bflo(tA3.w), bfhi(tA3.w));
  float2 fb0 = make_float2(bflo(tB0.x), bfhi(tB0.x)), fb1 = make_float2(bflo(tB0.y), bfhi(tB0.y));
  float2 fb2 = make_float2(bflo(tB0.z), bfhi(tB0.z)), fb3 = make_float2(bflo(tB0.w), bfhi(tB0.w));
  float2 fb4 = make_float2(bflo(tB1.x), bfhi(tB1.x)), fb5 = make_float2(bflo(tB1.y), bfhi(tB1.y));
  float2 fb6 = make_float2(bflo(tB1.z), bfhi(tB1.z)), fb7 = make_float2(bflo(tB1.w), bfhi(tB1.w));
  float2 fb8 = make_float2(bflo(tB2.x), bfhi(tB2.x)), fb9 = make_float2(bflo(tB2.y), bfhi(tB2.y));
  float2 fb10 = make_float2(bflo(tB2.z), bfhi(tB2.z)), fb11 = make_float2(bflo(tB2.w), bfhi(tB2.w));
  float2 fb12 = make_float2(bflo(tB3.x), bfhi(tB3.x)), fb13 = make_float2(bflo(tB3.y), bfhi(tB3.y));
  float2 fb14 = make_float2(bflo(tB3.z), bfhi(tB3.z)), fb15 = make_float2(bflo(tB3.w), bfhi(tB3.w));
#endif

  float a0i = start_w[2 * l] + start_b[2 * l];
  float a1i = start_w[2 * l + 1] + start_b[2 * l + 1];
  float m = fmaxf(a0i, a1i);
  #pragma unroll
  for (int s = 1; s < 64; s <<= 1) m = fmaxf(m, __shfl_xor(m, s, 64));
  float p0 = __expf(a0i - m), p1 = __expf(a1i - m);
  float tot = p0 + p1;
  #pragma unroll
  for (int s = 1; s < 64; s <<= 1) tot += __shfl_xor(tot, s, 64);
  float LLacc = m + __logf(tot);
  float inv = 1.0f / tot;
  uint ud = bfpack(p0 * inv, p1 * inv);

  uint qc0 = qtbl[(size_t)xrow[0] * 64 + l], qc1 = qtbl[(size_t)xrow[1] * 64 + l];
  uint qc2 = qtbl[(size_t)xrow[2] * 64 + l], qc3 = qtbl[(size_t)xrow[3] * 64 + l];
  uint qc4 = qtbl[(size_t)xrow[4] * 64 + l], qc5 = qtbl[(size_t)xrow[5] * 64 + l];
  uint qc6 = qtbl[(size_t)xrow[6] * 64 + l], qc7 = qtbl[(size_t)xrow[7] * 64 + l];
  int tk0 = xrow[8],  tk1 = xrow[9],  tk2 = xrow[10], tk3 = xrow[11];
  int tk4 = xrow[12], tk5 = xrow[13], tk6 = xrow[14], tk7 = xrow[15];

  for (int t8 = 0; t8 < 512; ++t8) {
    int tbase = t8 * 8;
    STEPF(0, 0) STEPF(1, 1) STEPF(2, 0) STEPF(3, 1)
    STEPF(4, 0) STEPF(5, 1) STEPF(6, 0) STEPF(7, 1)
  }
  if (l == 0 && wv == 0) chainLL[n] = LLacc;
}

// ---------- K4a: sum of Emax over all tokens ----------
__global__ __launch_bounds__(256) void k_emaxsum(const int* __restrict__ x,
    const float* __restrict__ Emax, float* __restrict__ sumE, int NT) {
  int idx = blockIdx.x * 256 + threadIdx.x;
  float s = 0.f;
  for (; idx < NT; idx += 128 * 256) s += Emax[x[idx]];
  #pragma unroll
  for (int mk = 1; mk < 64; mk <<= 1) s += __shfl_xor(s, mk, 64);
  if ((threadIdx.x & 63) == 0) atomicAdd(sumE, s);
}

// ---------- K4b: final scalar ----------
__global__ void k_final(const float* __restrict__ chainLL, const float* __restrict__ sumE,
                        float* __restrict__ out, int N) {
  int l = threadIdx.x;
  float v = (l < N) ? chainLL[l] : 0.f;
  #pragma unroll
  for (int mk = 1; mk < 64; mk <<= 1) v += __shfl_xor(v, mk, 64);
  if (l == 0) out[0] = -(v + sumE[0]) / (float)N;
}

extern "C" void kernel_launch(void* const* d_in, const int* in_sizes, int n_in,
                              void* d_out, int out_size, void* d_ws, size_t ws_size,
                              hipStream_t stream) {
  if (n_in < 6) return;
  const int*   x       = (const int*)d_in[0];
  const float* start_w = (const float*)d_in[1];
  const float* start_b = (const float*)d_in[2];
  const float* trans_w = (const float*)d_in[3];
  const float* emb_w   = (const float*)d_in[4];
  const float* vocab_w = (const float*)d_in[5];
  int NT = in_sizes[0];
  int N  = NT / 4096;
  int V  = in_sizes[5] / 128;

  char* ws = (char*)d_ws;
  float* S_glob  = (float*)(ws + 0);        // 128 f
  float* sumE    = (float*)(ws + 512);      // 1 f
  float* chainLL = (float*)(ws + 768);      // N f
  uint*  Tcol    = (uint*)(ws + 1024);      // 32 KB
  float* Emax    = (float*)(ws + 36864);    // V floats (ends 236864)
  float* LLseg   = (float*)(ws + 241664);   // N*8 floats
  uint*  qtbl    = (uint*)(ws + 262144);    // V*64 dwords = V*256 B
  size_t pst_off = 262144 + (size_t)V * 256;
  uint*  Pst     = (uint*)(ws + pst_off);   // N*8*8192 dwords
  size_t need    = pst_off + (size_t)N * 8 * 8192 * 4 + 64;

  hipMemsetAsync(d_ws, 0, 1024, stream);
  k_tran<<<dim3(1), dim3(128), 0, stream>>>(trans_w, Tcol);
  k_logits<<<dim3((V + 63) / 64), dim3(256), 0, stream>>>(emb_w, vocab_w, qtbl, S_glob, V);
  k_qtab<<<dim3((V + 3) / 4), dim3(256), 0, stream>>>(qtbl, S_glob, Emax, V);
  if (ws_size >= need) {
    k_seg<<<dim3(N * 8), dim3(256), 0, stream>>>(x, Tcol, qtbl, Pst, LLseg);
    k_comb<<<dim3(N), dim3(64), 0, stream>>>(start_w, start_b, Pst, LLseg, chainLL);
  } else {
    k_chain<<<dim3(N), dim3(256), 0, stream>>>(x, start_w, start_b, Tcol, qtbl, chainLL);
  }
  k_emaxsum<<<dim3(128), dim3(256), 0, stream>>>(x, Emax, sumE, NT);
  k_final<<<dim3(1), dim3(64), 0, stream>>>(chainLL, sumE, (float*)d_out, N);
}